// Round 1
// baseline (161.538 us; speedup 1.0000x reference)
//
#include <hip/hip_runtime.h>
#include <hip/hip_bf16.h>

#define EPSV 1e-3f

__device__ __forceinline__ float rcp_fast(float x){ return __builtin_amdgcn_rcpf(x); }
__device__ __forceinline__ float sigm(float x){
    x = fminf(fmaxf(x, -30.f), 30.f);
    return rcp_fast(1.f + __expf(-x));
}
__device__ __forceinline__ float tanh_fast(float x){
    x = fminf(fmaxf(x, -15.f), 15.f);
    float e = __expf(2.f * x);
    return 1.f - 2.f * rcp_fast(e + 1.f);
}

// Broadcast from lane (group_base + K) within an aligned 8-lane group.
// BitMode swizzle: and=0x18 keeps bits 3-4 (group id within 32-half), or=K sets bits 0-2.
template<int K>
__device__ __forceinline__ float bc8(float v){
    return __int_as_float(__builtin_amdgcn_ds_swizzle(__float_as_int(v), (K << 5) | 0x18));
}
#define BC8_ALL(dst, src) do { \
    dst[0]=bc8<0>(src); dst[1]=bc8<1>(src); dst[2]=bc8<2>(src); dst[3]=bc8<3>(src); \
    dst[4]=bc8<4>(src); dst[5]=bc8<5>(src); dst[6]=bc8<6>(src); dst[7]=bc8<7>(src); } while(0)

// ---------------- K1: stage-1 LSTM (tanh), 8 lanes per sample ----------------
// lane = sib*8 + d ; lane owns hidden unit d (gate columns {d, 8+d, 16+d, 24+d}).
__global__ __launch_bounds__(256) void k1_lstm0(
    const float* __restrict__ noise, const float* __restrict__ W0,
    const float* __restrict__ U0, const float* __restrict__ b0,
    float* __restrict__ Hbuf, float* __restrict__ Cbuf, double* __restrict__ stats1)
{
    const int tid = threadIdx.x;
    const int d = tid & 7;
    const size_t b = (size_t)blockIdx.x * 32 + (tid >> 3);

    float w0c[16][4], u0c[8][4], b0v[4];
    #pragma unroll
    for (int g = 0; g < 4; ++g) b0v[g] = b0[8*g + d];
    #pragma unroll
    for (int f = 0; f < 16; ++f)
        #pragma unroll
        for (int g = 0; g < 4; ++g) w0c[f][g] = W0[f*32 + 8*g + d];
    #pragma unroll
    for (int e = 0; e < 8; ++e)
        #pragma unroll
        for (int g = 0; g < 4; ++g) u0c[e][g] = U0[e*32 + 8*g + d];

    const float4* __restrict__ xrow = reinterpret_cast<const float4*>(noise + b * 512);
    float h = 0.f, c = 0.f;
    #pragma unroll 2
    for (int t = 0; t < 32; ++t){
        float4 q0 = xrow[t*4+0], q1 = xrow[t*4+1], q2 = xrow[t*4+2], q3 = xrow[t*4+3];
        float hall[8]; BC8_ALL(hall, h);
        const float x[16] = {q0.x,q0.y,q0.z,q0.w, q1.x,q1.y,q1.z,q1.w,
                             q2.x,q2.y,q2.z,q2.w, q3.x,q3.y,q3.z,q3.w};
        float z[4] = {b0v[0], b0v[1], b0v[2], b0v[3]};
        #pragma unroll
        for (int f = 0; f < 16; ++f)
            #pragma unroll
            for (int g = 0; g < 4; ++g) z[g] = fmaf(x[f], w0c[f][g], z[g]);
        #pragma unroll
        for (int e = 0; e < 8; ++e)
            #pragma unroll
            for (int g = 0; g < 4; ++g) z[g] = fmaf(hall[e], u0c[e][g], z[g]);
        // gate order i,f,g,o -> z[0..3] for this unit
        c = sigm(z[1])*c + sigm(z[0])*tanh_fast(z[2]);
        h = sigm(z[3])*tanh_fast(c);
    }
    Hbuf[(size_t)blockIdx.x*256 + tid] = h;  // == b*8 + d, fully coalesced
    Cbuf[(size_t)blockIdx.x*256 + tid] = c;

    // BN1 stats: per-d sums of h, h^2, c, c^2
    float v0 = h, v1 = h*h, v2 = c, v3 = c*c;
    v0 += __shfl_down(v0,32); v0 += __shfl_down(v0,16); v0 += __shfl_down(v0,8);
    v1 += __shfl_down(v1,32); v1 += __shfl_down(v1,16); v1 += __shfl_down(v1,8);
    v2 += __shfl_down(v2,32); v2 += __shfl_down(v2,16); v2 += __shfl_down(v2,8);
    v3 += __shfl_down(v3,32); v3 += __shfl_down(v3,16); v3 += __shfl_down(v3,8);
    __shared__ float red[4][4][8];
    const int w = tid >> 6;
    if ((tid & 63) < 8){ red[0][w][d]=v0; red[1][w][d]=v1; red[2][w][d]=v2; red[3][w][d]=v3; }
    __syncthreads();
    if (tid < 32){
        const int s = tid >> 3, dd = tid & 7;
        float acc = red[s][0][dd] + red[s][1][dd] + red[s][2][dd] + red[s][3][dd];
        atomicAdd(stats1 + s*8 + dd, (double)acc);
    }
}

// ---------------- K2: BN1-apply + 14-step AR LSTM (relu), BN3 sums only -------
__global__ __launch_bounds__(256) void k2_ar(
    const float* __restrict__ Hbuf, const float* __restrict__ Cbuf,
    const double* __restrict__ stats1,
    const float* __restrict__ gamma_h, const float* __restrict__ beta_h,
    const float* __restrict__ gamma_c, const float* __restrict__ beta_c,
    const float* __restrict__ W1, const float* __restrict__ U1, const float* __restrict__ b1,
    double* __restrict__ stats3, int B)
{
    const int tid = threadIdx.x;
    const int d = tid & 7;
    const double invB = 1.0 / (double)B;
    const float meanH = (float)(stats1[d]      * invB);
    const float eH2   = (float)(stats1[8 + d]  * invB);
    const float meanC = (float)(stats1[16 + d] * invB);
    const float eC2   = (float)(stats1[24 + d] * invB);
    const float aH = gamma_h[d] * rsqrtf(eH2 - meanH*meanH + EPSV);
    const float aC = gamma_c[d] * rsqrtf(eC2 - meanC*meanC + EPSV);
    const float bH = beta_h[d] - meanH*aH;
    const float bC = beta_c[d] - meanC*aC;
    float h = fmaf(Hbuf[(size_t)blockIdx.x*256 + tid], aH, bH);
    float c = fmaf(Cbuf[(size_t)blockIdx.x*256 + tid], aC, bC);

    float wc[8][4], bcv[4];
    #pragma unroll
    for (int g = 0; g < 4; ++g) bcv[g] = b1[8*g + d];
    #pragma unroll
    for (int e = 0; e < 8; ++e)
        #pragma unroll
        for (int g = 0; g < 4; ++g) wc[e][g] = W1[e*32 + 8*g + d] + U1[e*32 + 8*g + d];

    float s1 = 0.f, s2 = 0.f;
    #pragma unroll
    for (int r = 0; r < 14; ++r){
        float hall[8]; BC8_ALL(hall, h);
        float z[4] = {bcv[0], bcv[1], bcv[2], bcv[3]};
        #pragma unroll
        for (int e = 0; e < 8; ++e)
            #pragma unroll
            for (int g = 0; g < 4; ++g) z[g] = fmaf(hall[e], wc[e][g], z[g]);
        c = sigm(z[1])*c + sigm(z[0])*fmaxf(z[2], 0.f);
        h = sigm(z[3])*fmaxf(c, 0.f);
        s1 += h; s2 = fmaf(h, h, s2);
    }
    s1 += __shfl_down(s1,32); s1 += __shfl_down(s1,16); s1 += __shfl_down(s1,8);
    s2 += __shfl_down(s2,32); s2 += __shfl_down(s2,16); s2 += __shfl_down(s2,8);
    __shared__ float red[2][4][8];
    const int w = tid >> 6;
    if ((tid & 63) < 8){ red[0][w][d] = s1; red[1][w][d] = s2; }
    __syncthreads();
    if (tid < 16){
        const int s = tid >> 3, dd = tid & 7;
        float acc = red[s][0][dd] + red[s][1][dd] + red[s][2][dd] + red[s][3][dd];
        atomicAdd(stats3 + s*8 + dd, (double)acc);
    }
}

// ---------------- K3: recompute AR LSTM, BN3-apply, output LSTM (8->4) --------
__global__ __launch_bounds__(256) void k3_out(
    const float* __restrict__ Hbuf, const float* __restrict__ Cbuf,
    const double* __restrict__ stats1, const double* __restrict__ stats3,
    const float* __restrict__ gamma_h, const float* __restrict__ beta_h,
    const float* __restrict__ gamma_c, const float* __restrict__ beta_c,
    const float* __restrict__ W1, const float* __restrict__ U1, const float* __restrict__ b1,
    const float* __restrict__ gamma3, const float* __restrict__ beta3,
    const float* __restrict__ W2, const float* __restrict__ U2, const float* __restrict__ b2,
    float* __restrict__ out, int B)
{
    const int tid = threadIdx.x;
    const int d = tid & 7;
    const double invB = 1.0 / (double)B;
    const float meanH = (float)(stats1[d]      * invB);
    const float eH2   = (float)(stats1[8 + d]  * invB);
    const float meanC = (float)(stats1[16 + d] * invB);
    const float eC2   = (float)(stats1[24 + d] * invB);
    const float aH = gamma_h[d] * rsqrtf(eH2 - meanH*meanH + EPSV);
    const float aC = gamma_c[d] * rsqrtf(eC2 - meanC*meanC + EPSV);
    const float bH = beta_h[d] - meanH*aH;
    const float bC = beta_c[d] - meanC*aC;
    float h = fmaf(Hbuf[(size_t)blockIdx.x*256 + tid], aH, bH);
    float c = fmaf(Cbuf[(size_t)blockIdx.x*256 + tid], aC, bC);

    float wc[8][4], bcv[4];
    #pragma unroll
    for (int g = 0; g < 4; ++g) bcv[g] = b1[8*g + d];
    #pragma unroll
    for (int e = 0; e < 8; ++e)
        #pragma unroll
        for (int g = 0; g < 4; ++g) wc[e][g] = W1[e*32 + 8*g + d] + U1[e*32 + 8*g + d];

    float barh[14];
    #pragma unroll
    for (int r = 0; r < 14; ++r){
        float hall[8]; BC8_ALL(hall, h);
        float z[4] = {bcv[0], bcv[1], bcv[2], bcv[3]};
        #pragma unroll
        for (int e = 0; e < 8; ++e)
            #pragma unroll
            for (int g = 0; g < 4; ++g) z[g] = fmaf(hall[e], wc[e][g], z[g]);
        c = sigm(z[1])*c + sigm(z[0])*fmaxf(z[2], 0.f);
        h = sigm(z[3])*fmaxf(c, 0.f);
        barh[r] = h;
    }
    // BN3 over (B, ROWS)
    const double invN = 1.0 / ((double)B * 14.0);
    const float mean3 = (float)(stats3[d]     * invN);
    const float e32   = (float)(stats3[8 + d] * invN);
    const float a3 = gamma3[d] * rsqrtf(e32 - mean3*mean3 + EPSV);
    const float b3 = beta3[d] - mean3*a3;
    #pragma unroll
    for (int r = 0; r < 14; ++r) barh[r] = fmaf(barh[r], a3, b3);

    // output LSTM: Do=4; lanes 4-7 compute duplicates (q = d&3) so swizzles stay full-group
    const int q = d & 3;
    float w2c[8][4], u2c[4][4], b2v[4];
    #pragma unroll
    for (int g = 0; g < 4; ++g) b2v[g] = b2[4*g + q];
    #pragma unroll
    for (int e = 0; e < 8; ++e)
        #pragma unroll
        for (int g = 0; g < 4; ++g) w2c[e][g] = W2[e*16 + 4*g + q];
    #pragma unroll
    for (int e = 0; e < 4; ++e)
        #pragma unroll
        for (int g = 0; g < 4; ++g) u2c[e][g] = U2[e*16 + 4*g + q];

    float ho = 0.f, co = 0.f;
    const size_t obase = ((size_t)blockIdx.x*32 + (tid >> 3)) * 56;
    #pragma unroll
    for (int r = 0; r < 14; ++r){
        const float cur = barh[13 - r];            // bars = reversed hs
        float be[8]; BC8_ALL(be, cur);
        float h4[4];
        h4[0]=bc8<0>(ho); h4[1]=bc8<1>(ho); h4[2]=bc8<2>(ho); h4[3]=bc8<3>(ho);
        float z[4] = {b2v[0], b2v[1], b2v[2], b2v[3]};
        #pragma unroll
        for (int e = 0; e < 8; ++e)
            #pragma unroll
            for (int g = 0; g < 4; ++g) z[g] = fmaf(be[e], w2c[e][g], z[g]);
        #pragma unroll
        for (int e = 0; e < 4; ++e)
            #pragma unroll
            for (int g = 0; g < 4; ++g) z[g] = fmaf(h4[e], u2c[e][g], z[g]);
        co = sigm(z[1])*co + sigm(z[0])*fmaxf(z[2], 0.f);
        ho = sigm(z[3])*fmaxf(co, 0.f);
        if (d < 4) out[obase + r*4 + d] = ho;
    }
}

extern "C" void kernel_launch(void* const* d_in, const int* in_sizes, int n_in,
                              void* d_out, int out_size, void* d_ws, size_t ws_size,
                              hipStream_t stream)
{
    const float* noise   = (const float*)d_in[0];
    const float* W0      = (const float*)d_in[1];
    const float* U0      = (const float*)d_in[2];
    const float* b0      = (const float*)d_in[3];
    const float* gamma_h = (const float*)d_in[4];
    const float* beta_h  = (const float*)d_in[5];
    const float* gamma_c = (const float*)d_in[6];
    const float* beta_c  = (const float*)d_in[7];
    const float* W1      = (const float*)d_in[8];
    const float* U1      = (const float*)d_in[9];
    const float* b1      = (const float*)d_in[10];
    const float* gamma3  = (const float*)d_in[11];
    const float* beta3   = (const float*)d_in[12];
    const float* W2      = (const float*)d_in[13];
    const float* U2      = (const float*)d_in[14];
    const float* b2      = (const float*)d_in[15];

    const int B = in_sizes[0] / (32 * 16);   // 65536
    double* stats1 = (double*)d_ws;          // 32 doubles: Sh[8], Sh2[8], Sc[8], Sc2[8]
    double* stats3 = stats1 + 32;            // 16 doubles: Sb[8], Sb2[8]
    float* Hbuf = (float*)((char*)d_ws + 512);
    float* Cbuf = Hbuf + (size_t)B * 8;

    hipMemsetAsync(d_ws, 0, 48 * sizeof(double), stream);
    const int nb = B / 32;  // 2048 blocks x 256 threads, 8 lanes/sample
    k1_lstm0<<<nb, 256, 0, stream>>>(noise, W0, U0, b0, Hbuf, Cbuf, stats1);
    k2_ar<<<nb, 256, 0, stream>>>(Hbuf, Cbuf, stats1, gamma_h, beta_h, gamma_c, beta_c,
                                  W1, U1, b1, stats3, B);
    k3_out<<<nb, 256, 0, stream>>>(Hbuf, Cbuf, stats1, stats3, gamma_h, beta_h, gamma_c, beta_c,
                                   W1, U1, b1, gamma3, beta3, W2, U2, b2, (float*)d_out, B);
}

// Round 2
// 153.712 us; speedup vs baseline: 1.0509x; 1.0509x over previous
//
#include <hip/hip_runtime.h>
#include <hip/hip_bf16.h>

#define EPSV 1e-3f

__device__ __forceinline__ float rcp_fast(float x){ return __builtin_amdgcn_rcpf(x); }
// |z| is bounded (~<10) in this model: no clamps needed.
__device__ __forceinline__ float sigm(float x){
    return rcp_fast(1.f + __expf(-x));
}
__device__ __forceinline__ float tanh_fast(float x){
    float e = __expf(2.f * x);
    return 1.f - 2.f * rcp_fast(e + 1.f);
}

// Broadcast from lane (group_base + K) within an aligned 8-lane group.
// BitMode swizzle: and=0x18 keeps bits 3-4 (group id within 32-half), or=K sets bits 0-2.
template<int K>
__device__ __forceinline__ float bc8(float v){
    return __int_as_float(__builtin_amdgcn_ds_swizzle(__float_as_int(v), (K << 5) | 0x18));
}
#define BC8_ALL(dst, src) do { \
    dst[0]=bc8<0>(src); dst[1]=bc8<1>(src); dst[2]=bc8<2>(src); dst[3]=bc8<3>(src); \
    dst[4]=bc8<4>(src); dst[5]=bc8<5>(src); dst[6]=bc8<6>(src); dst[7]=bc8<7>(src); } while(0)

// ---------------- K1: stage-1 LSTM (tanh), 8 lanes per sample ----------------
// lane = sib*8 + d ; lane owns hidden unit d (gate columns {d, 8+d, 16+d, 24+d}).
// __launch_bounds__(256,2): <=256 VGPR so the ~100-float weight slice stays
// register-resident across the t-loop (68-VGPR default sank weight loads into
// the loop -> 130us). 2 waves/SIMD + explicit x prefetch hide HBM latency.
__global__ __launch_bounds__(256, 2) void k1_lstm0(
    const float* __restrict__ noise, const float* __restrict__ W0,
    const float* __restrict__ U0, const float* __restrict__ b0,
    float* __restrict__ Hbuf, float* __restrict__ Cbuf, double* __restrict__ stats1)
{
    const int tid = threadIdx.x;
    const int d = tid & 7;
    const size_t b = (size_t)blockIdx.x * 32 + (tid >> 3);

    float w0c[16][4], u0c[8][4], b0v[4];
    #pragma unroll
    for (int g = 0; g < 4; ++g) b0v[g] = b0[8*g + d];
    #pragma unroll
    for (int f = 0; f < 16; ++f)
        #pragma unroll
        for (int g = 0; g < 4; ++g) w0c[f][g] = W0[f*32 + 8*g + d];
    #pragma unroll
    for (int e = 0; e < 8; ++e)
        #pragma unroll
        for (int g = 0; g < 4; ++g) u0c[e][g] = U0[e*32 + 8*g + d];

    const float4* __restrict__ xrow = reinterpret_cast<const float4*>(noise + b * 512);
    float h = 0.f, c = 0.f;
    // software-pipelined x: load t+1 while computing t
    float4 q0 = xrow[0], q1 = xrow[1], q2 = xrow[2], q3 = xrow[3];
    #pragma unroll 2
    for (int t = 0; t < 32; ++t){
        const float x[16] = {q0.x,q0.y,q0.z,q0.w, q1.x,q1.y,q1.z,q1.w,
                             q2.x,q2.y,q2.z,q2.w, q3.x,q3.y,q3.z,q3.w};
        const int tn = (t + 1) & 31;
        q0 = xrow[tn*4+0]; q1 = xrow[tn*4+1]; q2 = xrow[tn*4+2]; q3 = xrow[tn*4+3];
        float hall[8]; BC8_ALL(hall, h);
        float z[4] = {b0v[0], b0v[1], b0v[2], b0v[3]};
        #pragma unroll
        for (int f = 0; f < 16; ++f)
            #pragma unroll
            for (int g = 0; g < 4; ++g) z[g] = fmaf(x[f], w0c[f][g], z[g]);
        #pragma unroll
        for (int e = 0; e < 8; ++e)
            #pragma unroll
            for (int g = 0; g < 4; ++g) z[g] = fmaf(hall[e], u0c[e][g], z[g]);
        // gate order i,f,g,o -> z[0..3] for this unit
        c = sigm(z[1])*c + sigm(z[0])*tanh_fast(z[2]);
        h = sigm(z[3])*tanh_fast(c);
    }
    Hbuf[(size_t)blockIdx.x*256 + tid] = h;  // == b*8 + d, fully coalesced
    Cbuf[(size_t)blockIdx.x*256 + tid] = c;

    // BN1 stats: per-d sums of h, h^2, c, c^2
    float v0 = h, v1 = h*h, v2 = c, v3 = c*c;
    v0 += __shfl_down(v0,32); v0 += __shfl_down(v0,16); v0 += __shfl_down(v0,8);
    v1 += __shfl_down(v1,32); v1 += __shfl_down(v1,16); v1 += __shfl_down(v1,8);
    v2 += __shfl_down(v2,32); v2 += __shfl_down(v2,16); v2 += __shfl_down(v2,8);
    v3 += __shfl_down(v3,32); v3 += __shfl_down(v3,16); v3 += __shfl_down(v3,8);
    __shared__ float red[4][4][8];
    const int w = tid >> 6;
    if ((tid & 63) < 8){ red[0][w][d]=v0; red[1][w][d]=v1; red[2][w][d]=v2; red[3][w][d]=v3; }
    __syncthreads();
    if (tid < 32){
        const int s = tid >> 3, dd = tid & 7;
        float acc = red[s][0][dd] + red[s][1][dd] + red[s][2][dd] + red[s][3][dd];
        atomicAdd(stats1 + s*8 + dd, (double)acc);
    }
}

// ---------------- K2: BN1-apply + 14-step AR LSTM (relu), BN3 sums only -------
__global__ __launch_bounds__(256) void k2_ar(
    const float* __restrict__ Hbuf, const float* __restrict__ Cbuf,
    const double* __restrict__ stats1,
    const float* __restrict__ gamma_h, const float* __restrict__ beta_h,
    const float* __restrict__ gamma_c, const float* __restrict__ beta_c,
    const float* __restrict__ W1, const float* __restrict__ U1, const float* __restrict__ b1,
    double* __restrict__ stats3, int B)
{
    const int tid = threadIdx.x;
    const int d = tid & 7;
    const double invB = 1.0 / (double)B;
    const float meanH = (float)(stats1[d]      * invB);
    const float eH2   = (float)(stats1[8 + d]  * invB);
    const float meanC = (float)(stats1[16 + d] * invB);
    const float eC2   = (float)(stats1[24 + d] * invB);
    const float aH = gamma_h[d] * rsqrtf(eH2 - meanH*meanH + EPSV);
    const float aC = gamma_c[d] * rsqrtf(eC2 - meanC*meanC + EPSV);
    const float bH = beta_h[d] - meanH*aH;
    const float bC = beta_c[d] - meanC*aC;
    float h = fmaf(Hbuf[(size_t)blockIdx.x*256 + tid], aH, bH);
    float c = fmaf(Cbuf[(size_t)blockIdx.x*256 + tid], aC, bC);

    float wc[8][4], bcv[4];
    #pragma unroll
    for (int g = 0; g < 4; ++g) bcv[g] = b1[8*g + d];
    #pragma unroll
    for (int e = 0; e < 8; ++e)
        #pragma unroll
        for (int g = 0; g < 4; ++g) wc[e][g] = W1[e*32 + 8*g + d] + U1[e*32 + 8*g + d];

    float s1 = 0.f, s2 = 0.f;
    #pragma unroll
    for (int r = 0; r < 14; ++r){
        float hall[8]; BC8_ALL(hall, h);
        float z[4] = {bcv[0], bcv[1], bcv[2], bcv[3]};
        #pragma unroll
        for (int e = 0; e < 8; ++e)
            #pragma unroll
            for (int g = 0; g < 4; ++g) z[g] = fmaf(hall[e], wc[e][g], z[g]);
        c = sigm(z[1])*c + sigm(z[0])*fmaxf(z[2], 0.f);
        h = sigm(z[3])*fmaxf(c, 0.f);
        s1 += h; s2 = fmaf(h, h, s2);
    }
    s1 += __shfl_down(s1,32); s1 += __shfl_down(s1,16); s1 += __shfl_down(s1,8);
    s2 += __shfl_down(s2,32); s2 += __shfl_down(s2,16); s2 += __shfl_down(s2,8);
    __shared__ float red[2][4][8];
    const int w = tid >> 6;
    if ((tid & 63) < 8){ red[0][w][d] = s1; red[1][w][d] = s2; }
    __syncthreads();
    if (tid < 16){
        const int s = tid >> 3, dd = tid & 7;
        float acc = red[s][0][dd] + red[s][1][dd] + red[s][2][dd] + red[s][3][dd];
        atomicAdd(stats3 + s*8 + dd, (double)acc);
    }
}

// ---------------- K3: recompute AR LSTM, BN3-apply, output LSTM (8->4) --------
// (256,2): keeps wc/w2c/u2c/barh (~100 floats) register-resident.
__global__ __launch_bounds__(256, 2) void k3_out(
    const float* __restrict__ Hbuf, const float* __restrict__ Cbuf,
    const double* __restrict__ stats1, const double* __restrict__ stats3,
    const float* __restrict__ gamma_h, const float* __restrict__ beta_h,
    const float* __restrict__ gamma_c, const float* __restrict__ beta_c,
    const float* __restrict__ W1, const float* __restrict__ U1, const float* __restrict__ b1,
    const float* __restrict__ gamma3, const float* __restrict__ beta3,
    const float* __restrict__ W2, const float* __restrict__ U2, const float* __restrict__ b2,
    float* __restrict__ out, int B)
{
    const int tid = threadIdx.x;
    const int d = tid & 7;
    const double invB = 1.0 / (double)B;
    const float meanH = (float)(stats1[d]      * invB);
    const float eH2   = (float)(stats1[8 + d]  * invB);
    const float meanC = (float)(stats1[16 + d] * invB);
    const float eC2   = (float)(stats1[24 + d] * invB);
    const float aH = gamma_h[d] * rsqrtf(eH2 - meanH*meanH + EPSV);
    const float aC = gamma_c[d] * rsqrtf(eC2 - meanC*meanC + EPSV);
    const float bH = beta_h[d] - meanH*aH;
    const float bC = beta_c[d] - meanC*aC;
    float h = fmaf(Hbuf[(size_t)blockIdx.x*256 + tid], aH, bH);
    float c = fmaf(Cbuf[(size_t)blockIdx.x*256 + tid], aC, bC);

    float wc[8][4], bcv[4];
    #pragma unroll
    for (int g = 0; g < 4; ++g) bcv[g] = b1[8*g + d];
    #pragma unroll
    for (int e = 0; e < 8; ++e)
        #pragma unroll
        for (int g = 0; g < 4; ++g) wc[e][g] = W1[e*32 + 8*g + d] + U1[e*32 + 8*g + d];

    float barh[14];
    #pragma unroll
    for (int r = 0; r < 14; ++r){
        float hall[8]; BC8_ALL(hall, h);
        float z[4] = {bcv[0], bcv[1], bcv[2], bcv[3]};
        #pragma unroll
        for (int e = 0; e < 8; ++e)
            #pragma unroll
            for (int g = 0; g < 4; ++g) z[g] = fmaf(hall[e], wc[e][g], z[g]);
        c = sigm(z[1])*c + sigm(z[0])*fmaxf(z[2], 0.f);
        h = sigm(z[3])*fmaxf(c, 0.f);
        barh[r] = h;
    }
    // BN3 over (B, ROWS)
    const double invN = 1.0 / ((double)B * 14.0);
    const float mean3 = (float)(stats3[d]     * invN);
    const float e32   = (float)(stats3[8 + d] * invN);
    const float a3 = gamma3[d] * rsqrtf(e32 - mean3*mean3 + EPSV);
    const float b3 = beta3[d] - mean3*a3;
    #pragma unroll
    for (int r = 0; r < 14; ++r) barh[r] = fmaf(barh[r], a3, b3);

    // output LSTM: Do=4; lanes 4-7 compute duplicates (q = d&3) so swizzles stay full-group
    const int q = d & 3;
    float w2c[8][4], u2c[4][4], b2v[4];
    #pragma unroll
    for (int g = 0; g < 4; ++g) b2v[g] = b2[4*g + q];
    #pragma unroll
    for (int e = 0; e < 8; ++e)
        #pragma unroll
        for (int g = 0; g < 4; ++g) w2c[e][g] = W2[e*16 + 4*g + q];
    #pragma unroll
    for (int e = 0; e < 4; ++e)
        #pragma unroll
        for (int g = 0; g < 4; ++g) u2c[e][g] = U2[e*16 + 4*g + q];

    float ho = 0.f, co = 0.f;
    const size_t obase = ((size_t)blockIdx.x*32 + (tid >> 3)) * 56;
    #pragma unroll
    for (int r = 0; r < 14; ++r){
        const float cur = barh[13 - r];            // bars = reversed hs
        float be[8]; BC8_ALL(be, cur);
        float h4[4];
        h4[0]=bc8<0>(ho); h4[1]=bc8<1>(ho); h4[2]=bc8<2>(ho); h4[3]=bc8<3>(ho);
        float z[4] = {b2v[0], b2v[1], b2v[2], b2v[3]};
        #pragma unroll
        for (int e = 0; e < 8; ++e)
            #pragma unroll
            for (int g = 0; g < 4; ++g) z[g] = fmaf(be[e], w2c[e][g], z[g]);
        #pragma unroll
        for (int e = 0; e < 4; ++e)
            #pragma unroll
            for (int g = 0; g < 4; ++g) z[g] = fmaf(h4[e], u2c[e][g], z[g]);
        co = sigm(z[1])*co + sigm(z[0])*fmaxf(z[2], 0.f);
        ho = sigm(z[3])*fmaxf(co, 0.f);
        if (d < 4) out[obase + r*4 + d] = ho;
    }
}

extern "C" void kernel_launch(void* const* d_in, const int* in_sizes, int n_in,
                              void* d_out, int out_size, void* d_ws, size_t ws_size,
                              hipStream_t stream)
{
    const float* noise   = (const float*)d_in[0];
    const float* W0      = (const float*)d_in[1];
    const float* U0      = (const float*)d_in[2];
    const float* b0      = (const float*)d_in[3];
    const float* gamma_h = (const float*)d_in[4];
    const float* beta_h  = (const float*)d_in[5];
    const float* gamma_c = (const float*)d_in[6];
    const float* beta_c  = (const float*)d_in[7];
    const float* W1      = (const float*)d_in[8];
    const float* U1      = (const float*)d_in[9];
    const float* b1      = (const float*)d_in[10];
    const float* gamma3  = (const float*)d_in[11];
    const float* beta3   = (const float*)d_in[12];
    const float* W2      = (const float*)d_in[13];
    const float* U2      = (const float*)d_in[14];
    const float* b2      = (const float*)d_in[15];

    const int B = in_sizes[0] / (32 * 16);   // 65536
    double* stats1 = (double*)d_ws;          // 32 doubles: Sh[8], Sh2[8], Sc[8], Sc2[8]
    double* stats3 = stats1 + 32;            // 16 doubles: Sb[8], Sb2[8]
    float* Hbuf = (float*)((char*)d_ws + 512);
    float* Cbuf = Hbuf + (size_t)B * 8;

    hipMemsetAsync(d_ws, 0, 48 * sizeof(double), stream);
    const int nb = B / 32;  // 2048 blocks x 256 threads, 8 lanes/sample
    k1_lstm0<<<nb, 256, 0, stream>>>(noise, W0, U0, b0, Hbuf, Cbuf, stats1);
    k2_ar<<<nb, 256, 0, stream>>>(Hbuf, Cbuf, stats1, gamma_h, beta_h, gamma_c, beta_c,
                                  W1, U1, b1, stats3, B);
    k3_out<<<nb, 256, 0, stream>>>(Hbuf, Cbuf, stats1, stats3, gamma_h, beta_h, gamma_c, beta_c,
                                   W1, U1, b1, gamma3, beta3, W2, U2, b2, (float*)d_out, B);
}